// Round 10
// baseline (937.309 us; speedup 1.0000x reference)
//
#include <hip/hip_runtime.h>

#define BB 2
#define NN 4096
#define NP 1024
#define MM 32
#define CC 35
#define CIN 32

// key-only DPP max-combine (u64 key = dist_bits<<32 | ~idx)
#define KEY_DPP(CTRL) do { \
    int _lo = (int)(unsigned)key, _hi = (int)(unsigned)(key >> 32); \
    int _olo = __builtin_amdgcn_mov_dpp(_lo, CTRL, 0xF, 0xF, true); \
    int _ohi = __builtin_amdgcn_mov_dpp(_hi, CTRL, 0xF, 0xF, true); \
    unsigned long long _ok = ((unsigned long long)(unsigned)_ohi << 32) | (unsigned)_olo; \
    if (_ok > key) key = _ok; \
} while (0)

// ---------------- FPS (blocks 0..BB-1) + weight-transpose prep (blocks BB..) ----
// 512 threads, 8 pts/thread. One-time 8x8x8 LDS bin-sort gives each thread a
// spatially compact cluster (centroid ctr, radius r). Per step, a wave whose
// 64 lanes ALL satisfy (d(ctr,c_new)-r)^2 > bv*1.0005 skips the dist update
// entirely (wave-uniform branch): skipped updates are provably no-ops
// (min(dist, d>=dist) == dist), so selection is bit-exact. Cached per-thread
// candidate key survives skipped steps. Reduce: DPP xor1/2/4/8 (row-16
// converged) -> 32 u64 slots -> barrier -> dual slot read + combine + 4 DPP.
__launch_bounds__(512)
__global__ void fps_prep_kernel(const float* __restrict__ xyz, float* __restrict__ newxyz_out,
                                const float* __restrict__ w1, const float* __restrict__ w2,
                                const float* __restrict__ w3,
                                float* __restrict__ w1T, float* __restrict__ w2T,
                                float* __restrict__ w3T)
{
#pragma clang fp contract(off)
    const int t = threadIdx.x;

    if (blockIdx.x >= BB) {   // ---- prep: transpose MLP weights ----
        int g = (blockIdx.x - BB) * 512 + t;
        int stride = 8 * 512;
        for (int i = g; i < 64 * CC; i += stride) { int o = i / CC, c = i % CC; w1T[c * 64 + o] = w1[i]; }
        for (int i = g; i < 64 * 64; i += stride) { int o = i >> 6, c = i & 63; w2T[c * 64 + o] = w2[i]; }
        for (int i = g; i < 128 * 64; i += stride) { int o = i >> 6, c = i & 63; w3T[c * 128 + o] = w3[i]; }
        return;
    }

    const int b = blockIdx.x;
    const float* xb = xyz + b * NN * 3;

    __shared__ float4 pc[NN];                  // coord table (orig idx), 64K
    __shared__ float  sxa[NN];                 // sorted x (aliased as nxs in loop)
    __shared__ float  sya[NN];
    __shared__ float  sza[NN];
    __shared__ int    sida[NN];                // sorted orig idx
    __shared__ int    cnt[512];                // histogram -> offsets
    __shared__ int    wsum[8];
    __shared__ unsigned long long red[2][32];  // double-buffered row winners
    float* nxs = sxa;                          // newxyz staging (setup arrays dead by then)

    // ---- setup: load, pc table, cell histogram ----
    float lx[8], ly[8], lz[8];
    int   lcell[8];
    cnt[t] = 0;                                // 512 threads, 512 cells
    __syncthreads();
#pragma unroll
    for (int k = 0; k < 8; ++k) {
        int n = t + 512 * k;
        float x = xb[n * 3 + 0];
        float y = xb[n * 3 + 1];
        float z = xb[n * 3 + 2];
        lx[k] = x; ly[k] = y; lz[k] = z;
        pc[n] = make_float4(x, y, z, 0.0f);
        int ix = min(7, (int)(x * 8.0f));
        int iy = min(7, (int)(y * 8.0f));
        int iz = min(7, (int)(z * 8.0f));
        lcell[k] = (iz << 6) | (iy << 3) | ix;
        atomicAdd(&cnt[lcell[k]], 1);
    }
    __syncthreads();

    // ---- exclusive prefix over 512 cells ----
    {
        int c = cnt[t];
        int incl = c;
        const int lane = t & 63, w = t >> 6;
#pragma unroll
        for (int off = 1; off < 64; off <<= 1) {
            int o = __shfl_up(incl, off);
            if (lane >= off) incl += o;
        }
        if (lane == 63) wsum[w] = incl;
        __syncthreads();
        int base = 0;
        for (int ww = 0; ww < 8; ++ww) if (ww < w) base += wsum[ww];
        int excl = base + incl - c;
        __syncthreads();               // everyone done reading cnt[t]
        cnt[t] = excl;
        __syncthreads();
    }

    // ---- scatter into sorted order ----
#pragma unroll
    for (int k = 0; k < 8; ++k) {
        int pos = atomicAdd(&cnt[lcell[k]], 1);
        sxa[pos] = lx[k];
        sya[pos] = ly[k];
        sza[pos] = lz[k];
        sida[pos] = t + 512 * k;
    }
    __syncthreads();

    // ---- own run: 8 consecutive sorted points; centroid + radius ----
    float px[8], py[8], pz[8], dist[8];
    unsigned lowk[8];
    float ctx = 0.0f, cty = 0.0f, ctz = 0.0f;
#pragma unroll
    for (int k = 0; k < 8; ++k) {
        int pos = 8 * t + k;
        px[k] = sxa[pos]; py[k] = sya[pos]; pz[k] = sza[pos];
        lowk[k] = 0xFFFFFFFFu - (unsigned)sida[pos];
        dist[k] = 1e10f;
        ctx += px[k]; cty += py[k]; ctz += pz[k];
    }
    ctx *= 0.125f; cty *= 0.125f; ctz *= 0.125f;
    float r2m = 0.0f;
#pragma unroll
    for (int k = 0; k < 8; ++k) {
        float dx = px[k] - ctx, dy = py[k] - cty, dz = pz[k] - ctz;
        float d2 = (dx * dx + dy * dy) + dz * dz;
        r2m = fmaxf(r2m, d2);
    }
    const float rr = sqrtf(r2m) * 1.0002f + 1e-7f;
    unsigned long long bkey =
        ((unsigned long long)(unsigned)__float_as_int(1e10f) << 32);  // bv=1e10 -> no skip
    __syncthreads();   // setup reads of s-arrays done before nxs aliasing writes

    int far = 0;
    for (int s = 0; s < NP; ++s) {
        float4 c = pc[far];                    // uniform LDS broadcast
        if (t == 0) {
            nxs[s * 3 + 0] = c.x;
            nxs[s * 3 + 1] = c.y;
            nxs[s * 3 + 2] = c.z;
        }
        const float cx = c.x, cy = c.y, cz = c.z;

        // cluster-level skip test (wave-uniform)
        float dxc = ctx - cx, dyc = cty - cy, dzc = ctz - cz;
        float d2c = (dxc * dxc + dyc * dyc) + dzc * dzc;
        float m = sqrtf(d2c) - rr;
        float bvf = __uint_as_float((unsigned)(bkey >> 32));
        int lane_skip = (m > 0.0f) && (m * m > bvf * 1.0005f);

        if (!__all(lane_skip)) {
            // full update for the wave (no-op for provably-safe lanes)
            unsigned long long nb = 0ull;
#pragma unroll
            for (int k = 0; k < 8; ++k) {
                float dx = px[k] - cx, dy = py[k] - cy, dz = pz[k] - cz;
                float d = (dx * dx + dy * dy) + dz * dz;
                float dd = fminf(dist[k], d);
                dist[k] = dd;
                unsigned long long kk =
                    ((unsigned long long)(unsigned)__float_as_int(dd) << 32) | lowk[k];
                if (kk > nb) nb = kk;
            }
            bkey = nb;
        }

        unsigned long long key = bkey;
        KEY_DPP(0xB1);   // xor 1
        KEY_DPP(0x4E);   // xor 2
        KEY_DPP(0x141);  // cross-quad combine
        KEY_DPP(0x140);  // cross-octet -> row of 16 converged

        const int buf = s & 1;
        if ((t & 15) == 0) red[buf][t >> 4] = key;   // 32 row winners
        __syncthreads();

        {
            unsigned long long k0 = red[buf][t & 15];
            unsigned long long k1 = red[buf][16 + (t & 15)];
            key = (k1 > k0) ? k1 : k0;
        }
        KEY_DPP(0xB1);
        KEY_DPP(0x4E);
        KEY_DPP(0x141);
        KEY_DPP(0x140);
        far = (int)(0xFFFFFFFFu - (unsigned)key);    // uniform across block
    }

    __syncthreads();
#pragma unroll
    for (int j = 0; j < 6; ++j) {
        int i = t + 512 * j;
        newxyz_out[b * NP * 3 + i] = nxs[i];
    }
}

// ---------------- kNN: one block per (b,p) ----------------
__launch_bounds__(256)
__global__ void knn_kernel(const float* __restrict__ xyz, const float* __restrict__ newxyz,
                           int* __restrict__ knn_out)
{
#pragma clang fp contract(off)
    const int bp = blockIdx.x;
    const int b = bp >> 10;
    const int t = threadIdx.x;
    const float* xb = xyz + b * NN * 3;

    const float qx = newxyz[bp * 3 + 0];
    const float qy = newxyz[bp * 3 + 1];
    const float qz = newxyz[bp * 3 + 2];
    const float qn = (qx * qx + qy * qy) + qz * qz;

    __shared__ float dist[NN];
    __shared__ float redV[4];
    __shared__ int   redI[4];

#pragma unroll
    for (int k = 0; k < 16; ++k) {
        int n = t + 256 * k;
        float x = xb[n * 3 + 0], y = xb[n * 3 + 1], z = xb[n * 3 + 2];
        float xn = (x * x + y * y) + z * z;
        float dt = (qx * x + qy * y) + qz * z;
        dist[n] = (qn + xn) - 2.0f * dt;
    }
    __syncthreads();

    for (int r = 0; r < MM; ++r) {
        float bv = 1e30f; int bi = NN;
#pragma unroll
        for (int k = 0; k < 16; ++k) {
            int n = t + 256 * k;
            float v = dist[n];
            if (v < bv) { bv = v; bi = n; }
        }
#pragma unroll
        for (int off = 1; off < 64; off <<= 1) {
            float ov = __shfl_xor(bv, off);
            int   oi = __shfl_xor(bi, off);
            if (ov < bv || (ov == bv && oi < bi)) { bv = ov; bi = oi; }
        }
        if ((t & 63) == 0) { redV[t >> 6] = bv; redI[t >> 6] = bi; }
        __syncthreads();
        bv = redV[0]; bi = redI[0];
#pragma unroll
        for (int w = 1; w < 4; ++w) {
            float ov = redV[w]; int oi = redI[w];
            if (ov < bv || (ov == bv && oi < bi)) { bv = ov; bi = oi; }
        }
        if (t == 0) { knn_out[bp * MM + r] = bi; dist[bi] = 1e30f; }
        __syncthreads();
    }
}

// ---------------- gather + AFA (u-factorized) + MLP + maxpool ----------------
__launch_bounds__(256)
__global__ void afa_mlp_kernel(const float* __restrict__ xyz, const float* __restrict__ feat,
                               const float* __restrict__ newxyz, const int* __restrict__ knn,
                               const float* __restrict__ aw1, const float* __restrict__ ab1,
                               const float* __restrict__ aw2, const float* __restrict__ ab2,
                               const float* __restrict__ aww, const float* __restrict__ abw,
                               const float* __restrict__ w1T, const float* __restrict__ b1,
                               const float* __restrict__ w2T, const float* __restrict__ b2,
                               const float* __restrict__ w3T, const float* __restrict__ b3,
                               float* __restrict__ out)
{
    const int bp = blockIdx.x;
    const int b = bp >> 10, p = bp & 1023;
    const int t = threadIdx.x;

    __shared__ int   idxs[MM];
    __shared__ float xs_t[MM][36];
    __shared__ float u_lds[MM][20];
    __shared__ float nfs[CC][MM];
    __shared__ float h1s[64][36];
    __shared__ float h2s[64][36];
    __shared__ float pmax[128][2];

    if (t < MM) idxs[t] = knn[bp * MM + t];
    __syncthreads();

    {   // gather x = concat(gxyz, gfeat) as [m][c]
        const int m = t & 31, c0 = t >> 5;
        const int id = idxs[m] & (NN - 1);
        for (int c = c0; c < CC; c += 8) {
            float v;
            if (c < 3) v = xyz[(b * NN + id) * 3 + c] - newxyz[bp * 3 + c];
            else       v = feat[(b * CIN + (c - 3)) * NN + id];
            xs_t[m][c] = v;
        }
        if (c0 == 0) xs_t[m][35] = 0.0f;
    }
    __syncthreads();

    const int i = t >> 3, jg = t & 7;

    float xi[36];
    {
        const float4* xp = (const float4*)&xs_t[i][0];
#pragma unroll
        for (int q = 0; q < 9; ++q) {
            float4 v = xp[q];
            xi[4 * q] = v.x; xi[4 * q + 1] = v.y; xi[4 * q + 2] = v.z; xi[4 * q + 3] = v.w;
        }
    }

    // phase A: u_i = W1 @ x_i
    float u16[16];
#pragma unroll
    for (int o = 0; o < 16; ++o) {
        float acc = 0.0f;
#pragma unroll
        for (int c = 0; c < CC; ++c) acc += aw1[o * CC + c] * xi[c];
        u16[o] = acc;
    }
    if (jg == 0) {
        float4* up = (float4*)&u_lds[i][0];
#pragma unroll
        for (int q = 0; q < 4; ++q)
            up[q] = make_float4(u16[4 * q], u16[4 * q + 1], u16[4 * q + 2], u16[4 * q + 3]);
    }
    __syncthreads();

    // phase B: per pair (i, j = jg+8*jk)
    float afa[CC];
#pragma unroll
    for (int c = 0; c < CC; ++c) afa[c] = 0.0f;

#pragma unroll
    for (int jk = 0; jk < 4; ++jk) {
        const int j = jg + 8 * jk;
        const bool diag = (i == j);

        float uj[16];
        {
            const float4* up = (const float4*)&u_lds[j][0];
#pragma unroll
            for (int q = 0; q < 4; ++q) {
                float4 v = up[q];
                uj[4 * q] = v.x; uj[4 * q + 1] = v.y; uj[4 * q + 2] = v.z; uj[4 * q + 3] = v.w;
            }
        }

        float h1[16];
#pragma unroll
        for (int o = 0; o < 16; ++o) {
            float sv = u16[o] - uj[o];
            if (diag) sv += u16[o];
            h1[o] = fmaxf(sv + ab1[o], 0.0f);
        }

        float xj[36];
        {
            const float4* xp = (const float4*)&xs_t[j][0];
#pragma unroll
            for (int q = 0; q < 9; ++q) {
                float4 v = xp[q];
                xj[4 * q] = v.x; xj[4 * q + 1] = v.y; xj[4 * q + 2] = v.z; xj[4 * q + 3] = v.w;
            }
        }

        float h2[16];
#pragma unroll
        for (int o = 0; o < 16; ++o) {
            float acc = ab2[o];
#pragma unroll
            for (int c = 0; c < 16; ++c) acc += aw2[o * 16 + c] * h1[c];
            h2[o] = fmaxf(acc, 0.0f);
        }

#pragma unroll
        for (int c = 0; c < CC; ++c) {
            float acc = abw[c];
#pragma unroll
            for (int k = 0; k < 16; ++k) acc += aww[c * 16 + k] * h2[k];
            float pc_ = xi[c] - xj[c];
            if (diag) pc_ += xi[c];
            afa[c] += pc_ * acc;
        }
    }

#pragma unroll
    for (int c = 0; c < CC; ++c) {
        float v = afa[c];
        v += __shfl_xor(v, 1);
        v += __shfl_xor(v, 2);
        v += __shfl_xor(v, 4);
        if (jg == 0) nfs[c][i] = xi[c] + v;
    }
    __syncthreads();

    // MLP layer 1: 35 -> 64
    {
        const int o = t & 63, ib = (t >> 6) << 3;
        float acc[8];
        float bb = b1[o];
#pragma unroll
        for (int k = 0; k < 8; ++k) acc[k] = bb;
        for (int c = 0; c < CC; ++c) {
            float w = w1T[c * 64 + o];
            const float4* np4 = (const float4*)&nfs[c][ib];
            float4 n0 = np4[0], n1 = np4[1];
            acc[0] += w * n0.x; acc[1] += w * n0.y; acc[2] += w * n0.z; acc[3] += w * n0.w;
            acc[4] += w * n1.x; acc[5] += w * n1.y; acc[6] += w * n1.z; acc[7] += w * n1.w;
        }
        float4 r0 = { fmaxf(acc[0], 0.0f), fmaxf(acc[1], 0.0f), fmaxf(acc[2], 0.0f), fmaxf(acc[3], 0.0f) };
        float4 r1 = { fmaxf(acc[4], 0.0f), fmaxf(acc[5], 0.0f), fmaxf(acc[6], 0.0f), fmaxf(acc[7], 0.0f) };
        *(float4*)&h1s[o][ib]     = r0;
        *(float4*)&h1s[o][ib + 4] = r1;
    }
    __syncthreads();

    // MLP layer 2: 64 -> 64
    {
        const int o = t & 63, ib = (t >> 6) << 3;
        float acc[8];
        float bb = b2[o];
#pragma unroll
        for (int k = 0; k < 8; ++k) acc[k] = bb;
        for (int c = 0; c < 64; ++c) {
            float w = w2T[c * 64 + o];
            const float4* hp4 = (const float4*)&h1s[c][ib];
            float4 h0 = hp4[0], h1v = hp4[1];
            acc[0] += w * h0.x; acc[1] += w * h0.y; acc[2] += w * h0.z; acc[3] += w * h0.w;
            acc[4] += w * h1v.x; acc[5] += w * h1v.y; acc[6] += w * h1v.z; acc[7] += w * h1v.w;
        }
        float4 r0 = { fmaxf(acc[0], 0.0f), fmaxf(acc[1], 0.0f), fmaxf(acc[2], 0.0f), fmaxf(acc[3], 0.0f) };
        float4 r1 = { fmaxf(acc[4], 0.0f), fmaxf(acc[5], 0.0f), fmaxf(acc[6], 0.0f), fmaxf(acc[7], 0.0f) };
        *(float4*)&h2s[o][ib]     = r0;
        *(float4*)&h2s[o][ib + 4] = r1;
    }
    __syncthreads();

    // MLP layer 3: 64 -> 128, relu, maxpool over M
    {
        const int o = t & 127, ib = (t >> 7) << 4;
        float acc[16];
        float bb = b3[o];
#pragma unroll
        for (int k = 0; k < 16; ++k) acc[k] = bb;
        for (int c = 0; c < 64; ++c) {
            float w = w3T[c * 128 + o];
            const float4* hp4 = (const float4*)&h2s[c][ib];
            float4 h0 = hp4[0], h1v = hp4[1], h2v = hp4[2], h3v = hp4[3];
            acc[0]  += w * h0.x;  acc[1]  += w * h0.y;  acc[2]  += w * h0.z;  acc[3]  += w * h0.w;
            acc[4]  += w * h1v.x; acc[5]  += w * h1v.y; acc[6]  += w * h1v.z; acc[7]  += w * h1v.w;
            acc[8]  += w * h2v.x; acc[9]  += w * h2v.y; acc[10] += w * h2v.z; acc[11] += w * h2v.w;
            acc[12] += w * h3v.x; acc[13] += w * h3v.y; acc[14] += w * h3v.z; acc[15] += w * h3v.w;
        }
        float mx = -1e30f;
#pragma unroll
        for (int k = 0; k < 16; ++k) mx = fmaxf(mx, fmaxf(acc[k], 0.0f));
        pmax[o][t >> 7] = mx;
    }
    __syncthreads();

    if (t < 128) {
        float v = fmaxf(pmax[t][0], pmax[t][1]);
        out[(b * 128 + t) * NP + p] = v;
    }
}

extern "C" void kernel_launch(void* const* d_in, const int* in_sizes, int n_in,
                              void* d_out, int out_size, void* d_ws, size_t ws_size,
                              hipStream_t stream)
{
    const float* xyz  = (const float*)d_in[0];
    const float* feat = (const float*)d_in[1];
    const float* aw1  = (const float*)d_in[2];
    const float* ab1  = (const float*)d_in[3];
    const float* aw2  = (const float*)d_in[4];
    const float* ab2  = (const float*)d_in[5];
    const float* aww  = (const float*)d_in[6];
    const float* abw  = (const float*)d_in[7];
    const float* mw1  = (const float*)d_in[8];
    const float* mb1  = (const float*)d_in[9];
    const float* mw2  = (const float*)d_in[10];
    const float* mb2  = (const float*)d_in[11];
    const float* mw3  = (const float*)d_in[12];
    const float* mb3  = (const float*)d_in[13];

    float* out    = (float*)d_out;
    float* newxyz = out;                  // (B, NP, 3) = 6144 floats
    float* out2   = out + BB * NP * 3;    // (B, 128, NP)

    int*   knn = (int*)d_ws;                                   // 2048*32 ints
    float* w1T = (float*)((char*)d_ws + (1 << 19));            // 35x64
    float* w2T = w1T + CC * 64;                                // 64x64
    float* w3T = w2T + 64 * 64;                                // 64x128

    fps_prep_kernel<<<dim3(BB + 8), dim3(512), 0, stream>>>(xyz, newxyz,
                                                            mw1, mw2, mw3, w1T, w2T, w3T);
    knn_kernel<<<dim3(BB * NP), dim3(256), 0, stream>>>(xyz, newxyz, knn);
    afa_mlp_kernel<<<dim3(BB * NP), dim3(256), 0, stream>>>(
        xyz, feat, newxyz, knn,
        aw1, ab1, aw2, ab2, aww, abw,
        w1T, mb1, w2T, mb2, w3T, mb3, out2);
}

// Round 11
// 769.421 us; speedup vs baseline: 1.2182x; 1.2182x over previous
//
#include <hip/hip_runtime.h>

#define BB 2
#define NN 4096
#define NP 1024
#define MM 32
#define CC 35
#define CIN 32

// key-only DPP max-combine (u64 key = dist_bits<<32 | ~idx)
#define KEY_DPP(CTRL) do { \
    int _lo = (int)(unsigned)key, _hi = (int)(unsigned)(key >> 32); \
    int _olo = __builtin_amdgcn_mov_dpp(_lo, CTRL, 0xF, 0xF, true); \
    int _ohi = __builtin_amdgcn_mov_dpp(_hi, CTRL, 0xF, 0xF, true); \
    unsigned long long _ok = ((unsigned long long)(unsigned)_ohi << 32) | (unsigned)_olo; \
    if (_ok > key) key = _ok; \
} while (0)

// ---------------- FPS (blocks 0..BB-1) + weight-transpose prep (blocks BB..) ----
// R9 structure verbatim (measured 612 us; R10's skip experiment regressed).
__launch_bounds__(256)
__global__ void fps_prep_kernel(const float* __restrict__ xyz, float* __restrict__ newxyz_out,
                                const float* __restrict__ w1, const float* __restrict__ w2,
                                const float* __restrict__ w3,
                                float* __restrict__ w1T, float* __restrict__ w2T,
                                float* __restrict__ w3T)
{
#pragma clang fp contract(off)
    const int t = threadIdx.x;

    if (blockIdx.x >= BB) {   // ---- prep: transpose MLP weights ----
        int g = (blockIdx.x - BB) * 256 + t;
        int stride = 8 * 256;
        for (int i = g; i < 64 * CC; i += stride) { int o = i / CC, c = i % CC; w1T[c * 64 + o] = w1[i]; }
        for (int i = g; i < 64 * 64; i += stride) { int o = i >> 6, c = i & 63; w2T[c * 64 + o] = w2[i]; }
        for (int i = g; i < 128 * 64; i += stride) { int o = i >> 6, c = i & 63; w3T[c * 128 + o] = w3[i]; }
        return;
    }

    const int b = blockIdx.x;
    const float* xb = xyz + b * NN * 3;

    __shared__ float4 pc[NN];                  // coord table for far-lookup
    __shared__ float nxs[NP * 3];              // newxyz staging
    __shared__ unsigned long long red[2][16];  // double-buffered row winners

    float px[16], py[16], pz[16], dist[16];
#pragma unroll
    for (int k = 0; k < 16; ++k) {
        int n = t + 256 * k;
        float x = xb[n * 3 + 0];
        float y = xb[n * 3 + 1];
        float z = xb[n * 3 + 2];
        px[k] = x; py[k] = y; pz[k] = z;
        dist[k] = 1e10f;
        pc[n] = make_float4(x, y, z, 0.0f);
    }
    __syncthreads();

    int far = 0;
    for (int s = 0; s < NP; ++s) {
        float4 c = pc[far];                    // uniform LDS broadcast
        if (t == 0) {
            nxs[s * 3 + 0] = c.x;
            nxs[s * 3 + 1] = c.y;
            nxs[s * 3 + 2] = c.z;
        }
        const float cx = c.x, cy = c.y, cz = c.z;

        float bv = -1.0f; int bi = 0;
#pragma unroll
        for (int k = 0; k < 16; ++k) {
            float dx = px[k] - cx, dy = py[k] - cy, dz = pz[k] - cz;
            float d = (dx * dx + dy * dy) + dz * dz;
            float dd = fminf(dist[k], d);
            dist[k] = dd;
            if (dd > bv) { bv = dd; bi = t + 256 * k; }
        }

        unsigned long long key =
            ((unsigned long long)(unsigned)__float_as_int(bv) << 32)
            | (unsigned)(0xFFFFFFFFu - (unsigned)bi);

        KEY_DPP(0xB1);   // xor 1
        KEY_DPP(0x4E);   // xor 2
        KEY_DPP(0x141);  // cross-quad combine
        KEY_DPP(0x140);  // cross-octet -> row of 16 converged

        const int buf = s & 1;
        if ((t & 15) == 0) red[buf][t >> 4] = key;
        __syncthreads();

        key = red[buf][t & 15];
        KEY_DPP(0xB1);
        KEY_DPP(0x4E);
        KEY_DPP(0x141);
        KEY_DPP(0x140);
        far = (int)(0xFFFFFFFFu - (unsigned)key);
    }

    __syncthreads();
#pragma unroll
    for (int j = 0; j < 12; ++j) {
        int i = t + 256 * j;
        newxyz_out[b * NP * 3 + i] = nxs[i];
    }
}

// ---------------- kNN via radix-select: one block per (b,p) ----------------
// Sortable key kx = float_bits ^ (sign? 0xFFFFFFFF : 0x80000000): unsigned
// order == float order (handles tiny negative dists from cancellation).
// Histogram on kx>>24 (256 buckets) -> prefix -> boundary bucket B with
// cum[<B] < 32 <= cum[<=B]. Points with bucket<B are all selected; exact
// remainder chosen by u64 (kx<<32|idx) rank-select inside bucket B (matches
// top_k's value-then-index stability). Output order within the 32 is
// irrelevant downstream (maxpool over M; AFA permutes i,j consistently).
__launch_bounds__(256)
__global__ void knn_kernel(const float* __restrict__ xyz, const float* __restrict__ newxyz,
                           int* __restrict__ knn_out)
{
#pragma clang fp contract(off)
    const int bp = blockIdx.x;
    const int b = bp >> 10;
    const int t = threadIdx.x;
    const float* xb = xyz + b * NN * 3;

    const float qx = newxyz[bp * 3 + 0];
    const float qy = newxyz[bp * 3 + 1];
    const float qz = newxyz[bp * 3 + 2];
    const float qn = (qx * qx + qy * qy) + qz * qz;

    __shared__ unsigned kxs[NN];               // sortable keys (16KB)
    __shared__ int hist[256];
    __shared__ int wsum[4];
    __shared__ unsigned long long blist[512];  // boundary-bucket members
    __shared__ int scal[4];                    // [0]=B [1]=cntBelow [2]=nB [3]=outcnt

    hist[t] = 0;
    if (t < 4) scal[t] = 0;
    __syncthreads();

#pragma unroll
    for (int k = 0; k < 16; ++k) {
        int n = t + 256 * k;
        float x = xb[n * 3 + 0], y = xb[n * 3 + 1], z = xb[n * 3 + 2];
        float xn = (x * x + y * y) + z * z;
        float dt = (qx * x + qy * y) + qz * z;
        float d = (qn + xn) - 2.0f * dt;
        unsigned bits = __float_as_uint(d);
        unsigned kx = bits ^ ((unsigned)((int)bits >> 31) | 0x80000000u);
        kxs[n] = kx;
        atomicAdd(&hist[kx >> 24], 1);
    }
    __syncthreads();

    // prefix over 256 buckets; locate boundary bucket
    {
        int c = hist[t];
        int incl = c;
        const int lane = t & 63, w = t >> 6;
#pragma unroll
        for (int off = 1; off < 64; off <<= 1) {
            int o = __shfl_up(incl, off);
            if (lane >= off) incl += o;
        }
        if (lane == 63) wsum[w] = incl;
        __syncthreads();
        int base = 0;
        for (int ww = 0; ww < 4; ++ww) if (ww < w) base += wsum[ww];
        int excl = base + incl - c;
        if (excl < MM && MM <= excl + c) { scal[0] = t; scal[1] = excl; }   // unique t
    }
    __syncthreads();

    const int B = scal[0];
    const int cntBelow = scal[1];
    const unsigned bstart = (unsigned)B << 24;

    // collect: below-boundary -> direct out; boundary bucket -> blist
#pragma unroll
    for (int k = 0; k < 16; ++k) {
        int n = t + 256 * k;
        unsigned kx = kxs[n];
        if (kx < bstart) {
            int pos = atomicAdd(&scal[3], 1);
            knn_out[bp * MM + pos] = n;
        } else if ((kx >> 24) == (unsigned)B) {
            int pos = atomicAdd(&scal[2], 1);
            if (pos < 512) blist[pos] = ((unsigned long long)kx << 32) | (unsigned)n;
        }
    }
    __syncthreads();

    const int nB = scal[2];
    const int k2 = MM - cntBelow;

    if (nB <= 512) {
        // exact rank-select among boundary members (u64 keys are unique via idx)
        for (int m = t; m < nB; m += 256) {
            unsigned long long my = blist[m];
            int rank = 0;
            for (int q = 0; q < nB; ++q) rank += (blist[q] < my) ? 1 : 0;
            if (rank < k2)
                knn_out[bp * MM + (cntBelow + rank)] = (int)(my & 0xFFFFFFFFu);
        }
    } else {
        // fallback (pathological duplicates): serial 32-round exact selection
        for (int r = 0; r < MM; ++r) {
            unsigned bvk = 0xFFFFFFFFu; int bi = NN;
#pragma unroll
            for (int k = 0; k < 16; ++k) {
                int n = t + 256 * k;
                unsigned v = kxs[n];
                if (v < bvk) { bvk = v; bi = n; }
            }
#pragma unroll
            for (int off = 1; off < 64; off <<= 1) {
                unsigned ov = __shfl_xor(bvk, off);
                int   oi = __shfl_xor(bi, off);
                if (ov < bvk || (ov == bvk && oi < bi)) { bvk = ov; bi = oi; }
            }
            if ((t & 63) == 0) { hist[t >> 6] = (int)bvk; wsum[t >> 6] = bi; }
            __syncthreads();
            unsigned fv = (unsigned)hist[0]; int fi = wsum[0];
#pragma unroll
            for (int w = 1; w < 4; ++w) {
                unsigned ov = (unsigned)hist[w]; int oi = wsum[w];
                if (ov < fv || (ov == fv && oi < fi)) { fv = ov; fi = oi; }
            }
            if (t == 0) { knn_out[bp * MM + r] = fi; kxs[fi] = 0xFFFFFFFFu; }
            __syncthreads();
        }
    }
}

// ---------------- gather + AFA (u-factorized) + MLP + maxpool ----------------
__launch_bounds__(256)
__global__ void afa_mlp_kernel(const float* __restrict__ xyz, const float* __restrict__ feat,
                               const float* __restrict__ newxyz, const int* __restrict__ knn,
                               const float* __restrict__ aw1, const float* __restrict__ ab1,
                               const float* __restrict__ aw2, const float* __restrict__ ab2,
                               const float* __restrict__ aww, const float* __restrict__ abw,
                               const float* __restrict__ w1T, const float* __restrict__ b1,
                               const float* __restrict__ w2T, const float* __restrict__ b2,
                               const float* __restrict__ w3T, const float* __restrict__ b3,
                               float* __restrict__ out)
{
    const int bp = blockIdx.x;
    const int b = bp >> 10, p = bp & 1023;
    const int t = threadIdx.x;

    __shared__ int   idxs[MM];
    __shared__ float xs_t[MM][36];
    __shared__ float u_lds[MM][20];
    __shared__ float nfs[CC][MM];
    __shared__ float h1s[64][36];
    __shared__ float h2s[64][36];
    __shared__ float pmax[128][2];

    if (t < MM) idxs[t] = knn[bp * MM + t];
    __syncthreads();

    {   // gather x = concat(gxyz, gfeat) as [m][c]
        const int m = t & 31, c0 = t >> 5;
        const int id = idxs[m] & (NN - 1);
        for (int c = c0; c < CC; c += 8) {
            float v;
            if (c < 3) v = xyz[(b * NN + id) * 3 + c] - newxyz[bp * 3 + c];
            else       v = feat[(b * CIN + (c - 3)) * NN + id];
            xs_t[m][c] = v;
        }
        if (c0 == 0) xs_t[m][35] = 0.0f;
    }
    __syncthreads();

    const int i = t >> 3, jg = t & 7;

    float xi[36];
    {
        const float4* xp = (const float4*)&xs_t[i][0];
#pragma unroll
        for (int q = 0; q < 9; ++q) {
            float4 v = xp[q];
            xi[4 * q] = v.x; xi[4 * q + 1] = v.y; xi[4 * q + 2] = v.z; xi[4 * q + 3] = v.w;
        }
    }

    // phase A: u_i = W1 @ x_i
    float u16[16];
#pragma unroll
    for (int o = 0; o < 16; ++o) {
        float acc = 0.0f;
#pragma unroll
        for (int c = 0; c < CC; ++c) acc += aw1[o * CC + c] * xi[c];
        u16[o] = acc;
    }
    if (jg == 0) {
        float4* up = (float4*)&u_lds[i][0];
#pragma unroll
        for (int q = 0; q < 4; ++q)
            up[q] = make_float4(u16[4 * q], u16[4 * q + 1], u16[4 * q + 2], u16[4 * q + 3]);
    }
    __syncthreads();

    // phase B: per pair (i, j = jg+8*jk)
    float afa[CC];
#pragma unroll
    for (int c = 0; c < CC; ++c) afa[c] = 0.0f;

#pragma unroll
    for (int jk = 0; jk < 4; ++jk) {
        const int j = jg + 8 * jk;
        const bool diag = (i == j);

        float uj[16];
        {
            const float4* up = (const float4*)&u_lds[j][0];
#pragma unroll
            for (int q = 0; q < 4; ++q) {
                float4 v = up[q];
                uj[4 * q] = v.x; uj[4 * q + 1] = v.y; uj[4 * q + 2] = v.z; uj[4 * q + 3] = v.w;
            }
        }

        float h1[16];
#pragma unroll
        for (int o = 0; o < 16; ++o) {
            float sv = u16[o] - uj[o];
            if (diag) sv += u16[o];
            h1[o] = fmaxf(sv + ab1[o], 0.0f);
        }

        float xj[36];
        {
            const float4* xp = (const float4*)&xs_t[j][0];
#pragma unroll
            for (int q = 0; q < 9; ++q) {
                float4 v = xp[q];
                xj[4 * q] = v.x; xj[4 * q + 1] = v.y; xj[4 * q + 2] = v.z; xj[4 * q + 3] = v.w;
            }
        }

        float h2[16];
#pragma unroll
        for (int o = 0; o < 16; ++o) {
            float acc = ab2[o];
#pragma unroll
            for (int c = 0; c < 16; ++c) acc += aw2[o * 16 + c] * h1[c];
            h2[o] = fmaxf(acc, 0.0f);
        }

#pragma unroll
        for (int c = 0; c < CC; ++c) {
            float acc = abw[c];
#pragma unroll
            for (int k = 0; k < 16; ++k) acc += aww[c * 16 + k] * h2[k];
            float pc_ = xi[c] - xj[c];
            if (diag) pc_ += xi[c];
            afa[c] += pc_ * acc;
        }
    }

#pragma unroll
    for (int c = 0; c < CC; ++c) {
        float v = afa[c];
        v += __shfl_xor(v, 1);
        v += __shfl_xor(v, 2);
        v += __shfl_xor(v, 4);
        if (jg == 0) nfs[c][i] = xi[c] + v;
    }
    __syncthreads();

    // MLP layer 1: 35 -> 64
    {
        const int o = t & 63, ib = (t >> 6) << 3;
        float acc[8];
        float bb = b1[o];
#pragma unroll
        for (int k = 0; k < 8; ++k) acc[k] = bb;
        for (int c = 0; c < CC; ++c) {
            float w = w1T[c * 64 + o];
            const float4* np4 = (const float4*)&nfs[c][ib];
            float4 n0 = np4[0], n1 = np4[1];
            acc[0] += w * n0.x; acc[1] += w * n0.y; acc[2] += w * n0.z; acc[3] += w * n0.w;
            acc[4] += w * n1.x; acc[5] += w * n1.y; acc[6] += w * n1.z; acc[7] += w * n1.w;
        }
        float4 r0 = { fmaxf(acc[0], 0.0f), fmaxf(acc[1], 0.0f), fmaxf(acc[2], 0.0f), fmaxf(acc[3], 0.0f) };
        float4 r1 = { fmaxf(acc[4], 0.0f), fmaxf(acc[5], 0.0f), fmaxf(acc[6], 0.0f), fmaxf(acc[7], 0.0f) };
        *(float4*)&h1s[o][ib]     = r0;
        *(float4*)&h1s[o][ib + 4] = r1;
    }
    __syncthreads();

    // MLP layer 2: 64 -> 64
    {
        const int o = t & 63, ib = (t >> 6) << 3;
        float acc[8];
        float bb = b2[o];
#pragma unroll
        for (int k = 0; k < 8; ++k) acc[k] = bb;
        for (int c = 0; c < 64; ++c) {
            float w = w2T[c * 64 + o];
            const float4* hp4 = (const float4*)&h1s[c][ib];
            float4 h0 = hp4[0], h1v = hp4[1];
            acc[0] += w * h0.x; acc[1] += w * h0.y; acc[2] += w * h0.z; acc[3] += w * h0.w;
            acc[4] += w * h1v.x; acc[5] += w * h1v.y; acc[6] += w * h1v.z; acc[7] += w * h1v.w;
        }
        float4 r0 = { fmaxf(acc[0], 0.0f), fmaxf(acc[1], 0.0f), fmaxf(acc[2], 0.0f), fmaxf(acc[3], 0.0f) };
        float4 r1 = { fmaxf(acc[4], 0.0f), fmaxf(acc[5], 0.0f), fmaxf(acc[6], 0.0f), fmaxf(acc[7], 0.0f) };
        *(float4*)&h2s[o][ib]     = r0;
        *(float4*)&h2s[o][ib + 4] = r1;
    }
    __syncthreads();

    // MLP layer 3: 64 -> 128, relu, maxpool over M
    {
        const int o = t & 127, ib = (t >> 7) << 4;
        float acc[16];
        float bb = b3[o];
#pragma unroll
        for (int k = 0; k < 16; ++k) acc[k] = bb;
        for (int c = 0; c < 64; ++c) {
            float w = w3T[c * 128 + o];
            const float4* hp4 = (const float4*)&h2s[c][ib];
            float4 h0 = hp4[0], h1v = hp4[1], h2v = hp4[2], h3v = hp4[3];
            acc[0]  += w * h0.x;  acc[1]  += w * h0.y;  acc[2]  += w * h0.z;  acc[3]  += w * h0.w;
            acc[4]  += w * h1v.x; acc[5]  += w * h1v.y; acc[6]  += w * h1v.z; acc[7]  += w * h1v.w;
            acc[8]  += w * h2v.x; acc[9]  += w * h2v.y; acc[10] += w * h2v.z; acc[11] += w * h2v.w;
            acc[12] += w * h3v.x; acc[13] += w * h3v.y; acc[14] += w * h3v.z; acc[15] += w * h3v.w;
        }
        float mx = -1e30f;
#pragma unroll
        for (int k = 0; k < 16; ++k) mx = fmaxf(mx, fmaxf(acc[k], 0.0f));
        pmax[o][t >> 7] = mx;
    }
    __syncthreads();

    if (t < 128) {
        float v = fmaxf(pmax[t][0], pmax[t][1]);
        out[(b * 128 + t) * NP + p] = v;
    }
}

extern "C" void kernel_launch(void* const* d_in, const int* in_sizes, int n_in,
                              void* d_out, int out_size, void* d_ws, size_t ws_size,
                              hipStream_t stream)
{
    const float* xyz  = (const float*)d_in[0];
    const float* feat = (const float*)d_in[1];
    const float* aw1  = (const float*)d_in[2];
    const float* ab1  = (const float*)d_in[3];
    const float* aw2  = (const float*)d_in[4];
    const float* ab2  = (const float*)d_in[5];
    const float* aww  = (const float*)d_in[6];
    const float* abw  = (const float*)d_in[7];
    const float* mw1  = (const float*)d_in[8];
    const float* mb1  = (const float*)d_in[9];
    const float* mw2  = (const float*)d_in[10];
    const float* mb2  = (const float*)d_in[11];
    const float* mw3  = (const float*)d_in[12];
    const float* mb3  = (const float*)d_in[13];

    float* out    = (float*)d_out;
    float* newxyz = out;                  // (B, NP, 3) = 6144 floats
    float* out2   = out + BB * NP * 3;    // (B, 128, NP)

    int*   knn = (int*)d_ws;                                   // 2048*32 ints
    float* w1T = (float*)((char*)d_ws + (1 << 19));            // 35x64
    float* w2T = w1T + CC * 64;                                // 64x64
    float* w3T = w2T + 64 * 64;                                // 64x128

    fps_prep_kernel<<<dim3(BB + 8), dim3(256), 0, stream>>>(xyz, newxyz,
                                                            mw1, mw2, mw3, w1T, w2T, w3T);
    knn_kernel<<<dim3(BB * NP), dim3(256), 0, stream>>>(xyz, newxyz, knn);
    afa_mlp_kernel<<<dim3(BB * NP), dim3(256), 0, stream>>>(
        xyz, feat, newxyz, knn,
        aw1, ab1, aw2, ab2, aww, abw,
        w1T, mb1, w2T, mb2, w3T, mb3, out2);
}

// Round 12
// 718.984 us; speedup vs baseline: 1.3037x; 1.0702x over previous
//
#include <hip/hip_runtime.h>

#define BB 2
#define NN 4096
#define NP 1024
#define MM 32
#define CC 35
#define CIN 32

typedef float f2 __attribute__((ext_vector_type(2)));

// key-only DPP max-combine (u64 key = dist_bits<<32 | ~idx)
#define KEY_DPP(CTRL) do { \
    int _lo = (int)(unsigned)key, _hi = (int)(unsigned)(key >> 32); \
    int _olo = __builtin_amdgcn_mov_dpp(_lo, CTRL, 0xF, 0xF, true); \
    int _ohi = __builtin_amdgcn_mov_dpp(_hi, CTRL, 0xF, 0xF, true); \
    unsigned long long _ok = ((unsigned long long)(unsigned)_ohi << 32) | (unsigned)_olo; \
    if (_ok > key) key = _ok; \
} while (0)

// ---------------- FPS (blocks 0..BB-1) + weight-transpose prep (blocks BB..) ----
// R9/R11 structure (612 us measured) with ONLY the update loop changed to
// f2 packed math (v_pk_add/mul/fma where backend allows): ~7 ops/pt vs 13,
// cutting the per-SIMD issue term 416 -> ~230 cy/step. Per-element FP ops
// identical (pk = 2 independent f32 lanes, contract off) -> bit-identical
// selection. A/B vs R11 disambiguates issue-bound vs latency-bound.
__launch_bounds__(256)
__global__ void fps_prep_kernel(const float* __restrict__ xyz, float* __restrict__ newxyz_out,
                                const float* __restrict__ w1, const float* __restrict__ w2,
                                const float* __restrict__ w3,
                                float* __restrict__ w1T, float* __restrict__ w2T,
                                float* __restrict__ w3T)
{
#pragma clang fp contract(off)
    const int t = threadIdx.x;

    if (blockIdx.x >= BB) {   // ---- prep: transpose MLP weights ----
        int g = (blockIdx.x - BB) * 256 + t;
        int stride = 8 * 256;
        for (int i = g; i < 64 * CC; i += stride) { int o = i / CC, c = i % CC; w1T[c * 64 + o] = w1[i]; }
        for (int i = g; i < 64 * 64; i += stride) { int o = i >> 6, c = i & 63; w2T[c * 64 + o] = w2[i]; }
        for (int i = g; i < 128 * 64; i += stride) { int o = i >> 6, c = i & 63; w3T[c * 128 + o] = w3[i]; }
        return;
    }

    const int b = blockIdx.x;
    const float* xb = xyz + b * NN * 3;

    __shared__ float4 pc[NN];                  // coord table for far-lookup
    __shared__ float nxs[NP * 3];              // newxyz staging
    __shared__ unsigned long long red[2][16];  // double-buffered row winners

    f2 px[8], py[8], pz[8], dist[8];
#pragma unroll
    for (int k = 0; k < 16; ++k) {
        int n = t + 256 * k;
        float x = xb[n * 3 + 0];
        float y = xb[n * 3 + 1];
        float z = xb[n * 3 + 2];
        px[k >> 1][k & 1] = x;
        py[k >> 1][k & 1] = y;
        pz[k >> 1][k & 1] = z;
        dist[k >> 1][k & 1] = 1e10f;
        pc[n] = make_float4(x, y, z, 0.0f);
    }
    __syncthreads();

    int far = 0;
    for (int s = 0; s < NP; ++s) {
        float4 c = pc[far];                    // uniform LDS broadcast
        if (t == 0) {
            nxs[s * 3 + 0] = c.x;
            nxs[s * 3 + 1] = c.y;
            nxs[s * 3 + 2] = c.z;
        }
        const f2 cx = { c.x, c.x }, cy = { c.y, c.y }, cz = { c.z, c.z };

        // packed update; scalar argmax compares (ascending order -> first-index ties)
        float bv = -1.0f; int bi = 0;
#pragma unroll
        for (int j = 0; j < 8; ++j) {
            f2 dx = px[j] - cx, dy = py[j] - cy, dz = pz[j] - cz;
            f2 d = (dx * dx + dy * dy) + dz * dz;
            f2 dd = __builtin_elementwise_min(dist[j], d);
            dist[j] = dd;
            if (dd.x > bv) { bv = dd.x; bi = t + 256 * (2 * j); }
            if (dd.y > bv) { bv = dd.y; bi = t + 256 * (2 * j + 1); }
        }

        unsigned long long key =
            ((unsigned long long)(unsigned)__float_as_int(bv) << 32)
            | (unsigned)(0xFFFFFFFFu - (unsigned)bi);

        KEY_DPP(0xB1);   // xor 1
        KEY_DPP(0x4E);   // xor 2
        KEY_DPP(0x141);  // cross-quad combine
        KEY_DPP(0x140);  // cross-octet -> row of 16 converged

        const int buf = s & 1;
        if ((t & 15) == 0) red[buf][t >> 4] = key;
        __syncthreads();

        key = red[buf][t & 15];
        KEY_DPP(0xB1);
        KEY_DPP(0x4E);
        KEY_DPP(0x141);
        KEY_DPP(0x140);
        far = (int)(0xFFFFFFFFu - (unsigned)key);
    }

    __syncthreads();
#pragma unroll
    for (int j = 0; j < 12; ++j) {
        int i = t + 256 * j;
        newxyz_out[b * NP * 3 + i] = nxs[i];
    }
}

// ---------------- kNN via radix-select: one block per (b,p) ----------------
__launch_bounds__(256)
__global__ void knn_kernel(const float* __restrict__ xyz, const float* __restrict__ newxyz,
                           int* __restrict__ knn_out)
{
#pragma clang fp contract(off)
    const int bp = blockIdx.x;
    const int b = bp >> 10;
    const int t = threadIdx.x;
    const float* xb = xyz + b * NN * 3;

    const float qx = newxyz[bp * 3 + 0];
    const float qy = newxyz[bp * 3 + 1];
    const float qz = newxyz[bp * 3 + 2];
    const float qn = (qx * qx + qy * qy) + qz * qz;

    __shared__ unsigned kxs[NN];               // sortable keys (16KB)
    __shared__ int hist[256];
    __shared__ int wsum[4];
    __shared__ unsigned long long blist[512];  // boundary-bucket members
    __shared__ int scal[4];                    // [0]=B [1]=cntBelow [2]=nB [3]=outcnt

    hist[t] = 0;
    if (t < 4) scal[t] = 0;
    __syncthreads();

#pragma unroll
    for (int k = 0; k < 16; ++k) {
        int n = t + 256 * k;
        float x = xb[n * 3 + 0], y = xb[n * 3 + 1], z = xb[n * 3 + 2];
        float xn = (x * x + y * y) + z * z;
        float dt = (qx * x + qy * y) + qz * z;
        float d = (qn + xn) - 2.0f * dt;
        unsigned bits = __float_as_uint(d);
        unsigned kx = bits ^ ((unsigned)((int)bits >> 31) | 0x80000000u);
        kxs[n] = kx;
        atomicAdd(&hist[kx >> 24], 1);
    }
    __syncthreads();

    // prefix over 256 buckets; locate boundary bucket
    {
        int c = hist[t];
        int incl = c;
        const int lane = t & 63, w = t >> 6;
#pragma unroll
        for (int off = 1; off < 64; off <<= 1) {
            int o = __shfl_up(incl, off);
            if (lane >= off) incl += o;
        }
        if (lane == 63) wsum[w] = incl;
        __syncthreads();
        int base = 0;
        for (int ww = 0; ww < 4; ++ww) if (ww < w) base += wsum[ww];
        int excl = base + incl - c;
        if (excl < MM && MM <= excl + c) { scal[0] = t; scal[1] = excl; }   // unique t
    }
    __syncthreads();

    const int B = scal[0];
    const int cntBelow = scal[1];
    const unsigned bstart = (unsigned)B << 24;

    // collect: below-boundary -> direct out; boundary bucket -> blist
#pragma unroll
    for (int k = 0; k < 16; ++k) {
        int n = t + 256 * k;
        unsigned kx = kxs[n];
        if (kx < bstart) {
            int pos = atomicAdd(&scal[3], 1);
            knn_out[bp * MM + pos] = n;
        } else if ((kx >> 24) == (unsigned)B) {
            int pos = atomicAdd(&scal[2], 1);
            if (pos < 512) blist[pos] = ((unsigned long long)kx << 32) | (unsigned)n;
        }
    }
    __syncthreads();

    const int nB = scal[2];
    const int k2 = MM - cntBelow;

    if (nB <= 512) {
        // exact rank-select among boundary members (u64 keys unique via idx)
        for (int m = t; m < nB; m += 256) {
            unsigned long long my = blist[m];
            int rank = 0;
            for (int q = 0; q < nB; ++q) rank += (blist[q] < my) ? 1 : 0;
            if (rank < k2)
                knn_out[bp * MM + (cntBelow + rank)] = (int)(my & 0xFFFFFFFFu);
        }
    } else {
        // fallback (pathological duplicates): serial 32-round exact selection
        for (int r = 0; r < MM; ++r) {
            unsigned bvk = 0xFFFFFFFFu; int bi = NN;
#pragma unroll
            for (int k = 0; k < 16; ++k) {
                int n = t + 256 * k;
                unsigned v = kxs[n];
                if (v < bvk) { bvk = v; bi = n; }
            }
#pragma unroll
            for (int off = 1; off < 64; off <<= 1) {
                unsigned ov = __shfl_xor(bvk, off);
                int   oi = __shfl_xor(bi, off);
                if (ov < bvk || (ov == bvk && oi < bi)) { bvk = ov; bi = oi; }
            }
            if ((t & 63) == 0) { hist[t >> 6] = (int)bvk; wsum[t >> 6] = bi; }
            __syncthreads();
            unsigned fv = (unsigned)hist[0]; int fi = wsum[0];
#pragma unroll
            for (int w = 1; w < 4; ++w) {
                unsigned ov = (unsigned)hist[w]; int oi = wsum[w];
                if (ov < fv || (ov == fv && oi < fi)) { fv = ov; fi = oi; }
            }
            if (t == 0) { knn_out[bp * MM + r] = fi; kxs[fi] = 0xFFFFFFFFu; }
            __syncthreads();
        }
    }
}

// ---------------- gather + AFA (u-factorized) + MLP + maxpool ----------------
__launch_bounds__(256)
__global__ void afa_mlp_kernel(const float* __restrict__ xyz, const float* __restrict__ feat,
                               const float* __restrict__ newxyz, const int* __restrict__ knn,
                               const float* __restrict__ aw1, const float* __restrict__ ab1,
                               const float* __restrict__ aw2, const float* __restrict__ ab2,
                               const float* __restrict__ aww, const float* __restrict__ abw,
                               const float* __restrict__ w1T, const float* __restrict__ b1,
                               const float* __restrict__ w2T, const float* __restrict__ b2,
                               const float* __restrict__ w3T, const float* __restrict__ b3,
                               float* __restrict__ out)
{
    const int bp = blockIdx.x;
    const int b = bp >> 10, p = bp & 1023;
    const int t = threadIdx.x;

    __shared__ int   idxs[MM];
    __shared__ float xs_t[MM][36];
    __shared__ float u_lds[MM][20];
    __shared__ float nfs[CC][MM];
    __shared__ float h1s[64][36];
    __shared__ float h2s[64][36];
    __shared__ float pmax[128][2];

    if (t < MM) idxs[t] = knn[bp * MM + t];
    __syncthreads();

    {   // gather x = concat(gxyz, gfeat) as [m][c]
        const int m = t & 31, c0 = t >> 5;
        const int id = idxs[m] & (NN - 1);
        for (int c = c0; c < CC; c += 8) {
            float v;
            if (c < 3) v = xyz[(b * NN + id) * 3 + c] - newxyz[bp * 3 + c];
            else       v = feat[(b * CIN + (c - 3)) * NN + id];
            xs_t[m][c] = v;
        }
        if (c0 == 0) xs_t[m][35] = 0.0f;
    }
    __syncthreads();

    const int i = t >> 3, jg = t & 7;

    float xi[36];
    {
        const float4* xp = (const float4*)&xs_t[i][0];
#pragma unroll
        for (int q = 0; q < 9; ++q) {
            float4 v = xp[q];
            xi[4 * q] = v.x; xi[4 * q + 1] = v.y; xi[4 * q + 2] = v.z; xi[4 * q + 3] = v.w;
        }
    }

    // phase A: u_i = W1 @ x_i
    float u16[16];
#pragma unroll
    for (int o = 0; o < 16; ++o) {
        float acc = 0.0f;
#pragma unroll
        for (int c = 0; c < CC; ++c) acc += aw1[o * CC + c] * xi[c];
        u16[o] = acc;
    }
    if (jg == 0) {
        float4* up = (float4*)&u_lds[i][0];
#pragma unroll
        for (int q = 0; q < 4; ++q)
            up[q] = make_float4(u16[4 * q], u16[4 * q + 1], u16[4 * q + 2], u16[4 * q + 3]);
    }
    __syncthreads();

    // phase B: per pair (i, j = jg+8*jk)
    float afa[CC];
#pragma unroll
    for (int c = 0; c < CC; ++c) afa[c] = 0.0f;

#pragma unroll
    for (int jk = 0; jk < 4; ++jk) {
        const int j = jg + 8 * jk;
        const bool diag = (i == j);

        float uj[16];
        {
            const float4* up = (const float4*)&u_lds[j][0];
#pragma unroll
            for (int q = 0; q < 4; ++q) {
                float4 v = up[q];
                uj[4 * q] = v.x; uj[4 * q + 1] = v.y; uj[4 * q + 2] = v.z; uj[4 * q + 3] = v.w;
            }
        }

        float h1[16];
#pragma unroll
        for (int o = 0; o < 16; ++o) {
            float sv = u16[o] - uj[o];
            if (diag) sv += u16[o];
            h1[o] = fmaxf(sv + ab1[o], 0.0f);
        }

        float xj[36];
        {
            const float4* xp = (const float4*)&xs_t[j][0];
#pragma unroll
            for (int q = 0; q < 9; ++q) {
                float4 v = xp[q];
                xj[4 * q] = v.x; xj[4 * q + 1] = v.y; xj[4 * q + 2] = v.z; xj[4 * q + 3] = v.w;
            }
        }

        float h2[16];
#pragma unroll
        for (int o = 0; o < 16; ++o) {
            float acc = ab2[o];
#pragma unroll
            for (int c = 0; c < 16; ++c) acc += aw2[o * 16 + c] * h1[c];
            h2[o] = fmaxf(acc, 0.0f);
        }

#pragma unroll
        for (int c = 0; c < CC; ++c) {
            float acc = abw[c];
#pragma unroll
            for (int k = 0; k < 16; ++k) acc += aww[c * 16 + k] * h2[k];
            float pc_ = xi[c] - xj[c];
            if (diag) pc_ += xi[c];
            afa[c] += pc_ * acc;
        }
    }

#pragma unroll
    for (int c = 0; c < CC; ++c) {
        float v = afa[c];
        v += __shfl_xor(v, 1);
        v += __shfl_xor(v, 2);
        v += __shfl_xor(v, 4);
        if (jg == 0) nfs[c][i] = xi[c] + v;
    }
    __syncthreads();

    // MLP layer 1: 35 -> 64
    {
        const int o = t & 63, ib = (t >> 6) << 3;
        float acc[8];
        float bb = b1[o];
#pragma unroll
        for (int k = 0; k < 8; ++k) acc[k] = bb;
        for (int c = 0; c < CC; ++c) {
            float w = w1T[c * 64 + o];
            const float4* np4 = (const float4*)&nfs[c][ib];
            float4 n0 = np4[0], n1 = np4[1];
            acc[0] += w * n0.x; acc[1] += w * n0.y; acc[2] += w * n0.z; acc[3] += w * n0.w;
            acc[4] += w * n1.x; acc[5] += w * n1.y; acc[6] += w * n1.z; acc[7] += w * n1.w;
        }
        float4 r0 = { fmaxf(acc[0], 0.0f), fmaxf(acc[1], 0.0f), fmaxf(acc[2], 0.0f), fmaxf(acc[3], 0.0f) };
        float4 r1 = { fmaxf(acc[4], 0.0f), fmaxf(acc[5], 0.0f), fmaxf(acc[6], 0.0f), fmaxf(acc[7], 0.0f) };
        *(float4*)&h1s[o][ib]     = r0;
        *(float4*)&h1s[o][ib + 4] = r1;
    }
    __syncthreads();

    // MLP layer 2: 64 -> 64
    {
        const int o = t & 63, ib = (t >> 6) << 3;
        float acc[8];
        float bb = b2[o];
#pragma unroll
        for (int k = 0; k < 8; ++k) acc[k] = bb;
        for (int c = 0; c < 64; ++c) {
            float w = w2T[c * 64 + o];
            const float4* hp4 = (const float4*)&h1s[c][ib];
            float4 h0 = hp4[0], h1v = hp4[1];
            acc[0] += w * h0.x; acc[1] += w * h0.y; acc[2] += w * h0.z; acc[3] += w * h0.w;
            acc[4] += w * h1v.x; acc[5] += w * h1v.y; acc[6] += w * h1v.z; acc[7] += w * h1v.w;
        }
        float4 r0 = { fmaxf(acc[0], 0.0f), fmaxf(acc[1], 0.0f), fmaxf(acc[2], 0.0f), fmaxf(acc[3], 0.0f) };
        float4 r1 = { fmaxf(acc[4], 0.0f), fmaxf(acc[5], 0.0f), fmaxf(acc[6], 0.0f), fmaxf(acc[7], 0.0f) };
        *(float4*)&h2s[o][ib]     = r0;
        *(float4*)&h2s[o][ib + 4] = r1;
    }
    __syncthreads();

    // MLP layer 3: 64 -> 128, relu, maxpool over M
    {
        const int o = t & 127, ib = (t >> 7) << 4;
        float acc[16];
        float bb = b3[o];
#pragma unroll
        for (int k = 0; k < 16; ++k) acc[k] = bb;
        for (int c = 0; c < 64; ++c) {
            float w = w3T[c * 128 + o];
            const float4* hp4 = (const float4*)&h2s[c][ib];
            float4 h0 = hp4[0], h1v = hp4[1], h2v = hp4[2], h3v = hp4[3];
            acc[0]  += w * h0.x;  acc[1]  += w * h0.y;  acc[2]  += w * h0.z;  acc[3]  += w * h0.w;
            acc[4]  += w * h1v.x; acc[5]  += w * h1v.y; acc[6]  += w * h1v.z; acc[7]  += w * h1v.w;
            acc[8]  += w * h2v.x; acc[9]  += w * h2v.y; acc[10] += w * h2v.z; acc[11] += w * h2v.w;
            acc[12] += w * h3v.x; acc[13] += w * h3v.y; acc[14] += w * h3v.z; acc[15] += w * h3v.w;
        }
        float mx = -1e30f;
#pragma unroll
        for (int k = 0; k < 16; ++k) mx = fmaxf(mx, fmaxf(acc[k], 0.0f));
        pmax[o][t >> 7] = mx;
    }
    __syncthreads();

    if (t < 128) {
        float v = fmaxf(pmax[t][0], pmax[t][1]);
        out[(b * 128 + t) * NP + p] = v;
    }
}

extern "C" void kernel_launch(void* const* d_in, const int* in_sizes, int n_in,
                              void* d_out, int out_size, void* d_ws, size_t ws_size,
                              hipStream_t stream)
{
    const float* xyz  = (const float*)d_in[0];
    const float* feat = (const float*)d_in[1];
    const float* aw1  = (const float*)d_in[2];
    const float* ab1  = (const float*)d_in[3];
    const float* aw2  = (const float*)d_in[4];
    const float* ab2  = (const float*)d_in[5];
    const float* aww  = (const float*)d_in[6];
    const float* abw  = (const float*)d_in[7];
    const float* mw1  = (const float*)d_in[8];
    const float* mb1  = (const float*)d_in[9];
    const float* mw2  = (const float*)d_in[10];
    const float* mb2  = (const float*)d_in[11];
    const float* mw3  = (const float*)d_in[12];
    const float* mb3  = (const float*)d_in[13];

    float* out    = (float*)d_out;
    float* newxyz = out;                  // (B, NP, 3) = 6144 floats
    float* out2   = out + BB * NP * 3;    // (B, 128, NP)

    int*   knn = (int*)d_ws;                                   // 2048*32 ints
    float* w1T = (float*)((char*)d_ws + (1 << 19));            // 35x64
    float* w2T = w1T + CC * 64;                                // 64x64
    float* w3T = w2T + 64 * 64;                                // 64x128

    fps_prep_kernel<<<dim3(BB + 8), dim3(256), 0, stream>>>(xyz, newxyz,
                                                            mw1, mw2, mw3, w1T, w2T, w3T);
    knn_kernel<<<dim3(BB * NP), dim3(256), 0, stream>>>(xyz, newxyz, knn);
    afa_mlp_kernel<<<dim3(BB * NP), dim3(256), 0, stream>>>(
        xyz, feat, newxyz, knn,
        aw1, ab1, aw2, ab2, aww, abw,
        w1T, mb1, w2T, mb2, w3T, mb3, out2);
}

// Round 13
// 715.634 us; speedup vs baseline: 1.3098x; 1.0047x over previous
//
#include <hip/hip_runtime.h>

#define BB 2
#define NN 4096
#define NP 1024
#define MM 32
#define CC 35
#define CIN 32

typedef float f2 __attribute__((ext_vector_type(2)));

// key-only DPP max-combine (u64 key = dist_bits<<32 | ~idx)
#define KEY_DPP(CTRL) do { \
    int _lo = (int)(unsigned)key, _hi = (int)(unsigned)(key >> 32); \
    int _olo = __builtin_amdgcn_mov_dpp(_lo, CTRL, 0xF, 0xF, true); \
    int _ohi = __builtin_amdgcn_mov_dpp(_hi, CTRL, 0xF, 0xF, true); \
    unsigned long long _ok = ((unsigned long long)(unsigned)_ohi << 32) | (unsigned)_olo; \
    if (_ok > key) key = _ok; \
} while (0)

// ---------------- FPS (blocks 0..BB-1) + packed-weight prep (blocks BB..) ----
// fps: FROZEN R12 structure (563 us measured). prep: packed [c/4][o][4]
// layouts so MLP weight reads become one coalesced b128 per 4 c-iters.
__launch_bounds__(256)
__global__ void fps_prep_kernel(const float* __restrict__ xyz, float* __restrict__ newxyz_out,
                                const float* __restrict__ w1, const float* __restrict__ w2,
                                const float* __restrict__ w3,
                                float* __restrict__ w1p, float* __restrict__ w2p,
                                float* __restrict__ w3p)
{
#pragma clang fp contract(off)
    const int t = threadIdx.x;

    if (blockIdx.x >= BB) {   // ---- prep: pack MLP weights as [c4][o][4] ----
        int g = (blockIdx.x - BB) * 256 + t;
        int stride = 8 * 256;
        for (int i = g; i < 9 * 64 * 4; i += stride) {      // w1: 64x35 -> [9][64][4], pad c=35..36 with 0
            int c4 = i >> 8, o = (i >> 2) & 63, cl = i & 3;
            int c = 4 * c4 + cl;
            w1p[i] = (c < CC) ? w1[o * CC + c] : 0.0f;
        }
        for (int i = g; i < 16 * 64 * 4; i += stride) {     // w2: 64x64 -> [16][64][4]
            int c4 = i >> 8, o = (i >> 2) & 63, cl = i & 3;
            w2p[i] = w2[o * 64 + 4 * c4 + cl];
        }
        for (int i = g; i < 16 * 128 * 4; i += stride) {    // w3: 128x64 -> [16][128][4]
            int c4 = i >> 9, o = (i >> 2) & 127, cl = i & 3;
            w3p[i] = w3[o * 64 + 4 * c4 + cl];
        }
        return;
    }

    const int b = blockIdx.x;
    const float* xb = xyz + b * NN * 3;

    __shared__ float4 pc[NN];                  // coord table for far-lookup
    __shared__ float nxs[NP * 3];              // newxyz staging
    __shared__ unsigned long long red[2][16];  // double-buffered row winners

    f2 px[8], py[8], pz[8], dist[8];
#pragma unroll
    for (int k = 0; k < 16; ++k) {
        int n = t + 256 * k;
        float x = xb[n * 3 + 0];
        float y = xb[n * 3 + 1];
        float z = xb[n * 3 + 2];
        px[k >> 1][k & 1] = x;
        py[k >> 1][k & 1] = y;
        pz[k >> 1][k & 1] = z;
        dist[k >> 1][k & 1] = 1e10f;
        pc[n] = make_float4(x, y, z, 0.0f);
    }
    __syncthreads();

    int far = 0;
    for (int s = 0; s < NP; ++s) {
        float4 c = pc[far];                    // uniform LDS broadcast
        if (t == 0) {
            nxs[s * 3 + 0] = c.x;
            nxs[s * 3 + 1] = c.y;
            nxs[s * 3 + 2] = c.z;
        }
        const f2 cx = { c.x, c.x }, cy = { c.y, c.y }, cz = { c.z, c.z };

        // packed update; scalar argmax compares (ascending order -> first-index ties)
        float bv = -1.0f; int bi = 0;
#pragma unroll
        for (int j = 0; j < 8; ++j) {
            f2 dx = px[j] - cx, dy = py[j] - cy, dz = pz[j] - cz;
            f2 d = (dx * dx + dy * dy) + dz * dz;
            f2 dd = __builtin_elementwise_min(dist[j], d);
            dist[j] = dd;
            if (dd.x > bv) { bv = dd.x; bi = t + 256 * (2 * j); }
            if (dd.y > bv) { bv = dd.y; bi = t + 256 * (2 * j + 1); }
        }

        unsigned long long key =
            ((unsigned long long)(unsigned)__float_as_int(bv) << 32)
            | (unsigned)(0xFFFFFFFFu - (unsigned)bi);

        KEY_DPP(0xB1);   // xor 1
        KEY_DPP(0x4E);   // xor 2
        KEY_DPP(0x141);  // cross-quad combine
        KEY_DPP(0x140);  // cross-octet -> row of 16 converged

        const int buf = s & 1;
        if ((t & 15) == 0) red[buf][t >> 4] = key;
        __syncthreads();

        key = red[buf][t & 15];
        KEY_DPP(0xB1);
        KEY_DPP(0x4E);
        KEY_DPP(0x141);
        KEY_DPP(0x140);
        far = (int)(0xFFFFFFFFu - (unsigned)key);
    }

    __syncthreads();
#pragma unroll
    for (int j = 0; j < 12; ++j) {
        int i = t + 256 * j;
        newxyz_out[b * NP * 3 + i] = nxs[i];
    }
}

// ---------------- fused radix-kNN + gather + AFA + MLP + maxpool ----------------
// knn (radix-select, R11-proven) keeps idxs in LDS; its buffers UNION with
// the afa buffers (sequential phases) -> 31.4KB total, 5 blocks/CU by LDS.
// afa: u-split across jg (each (i,o) computed once, same c-order -> bit-
// identical) + packed b128 weight loads.
__launch_bounds__(256)
__global__ void knnafa_kernel(const float* __restrict__ xyz, const float* __restrict__ feat,
                              const float* __restrict__ newxyz,
                              const float* __restrict__ aw1, const float* __restrict__ ab1,
                              const float* __restrict__ aw2, const float* __restrict__ ab2,
                              const float* __restrict__ aww, const float* __restrict__ abw,
                              const float* __restrict__ w1p, const float* __restrict__ b1,
                              const float* __restrict__ w2p, const float* __restrict__ b2,
                              const float* __restrict__ w3p, const float* __restrict__ b3,
                              float* __restrict__ out)
{
    const int bp = blockIdx.x;
    const int b = bp >> 10, p = bp & 1023;
    const int t = threadIdx.x;

    union Smem {
        struct {
            unsigned kxs[NN];                  // 16KB sortable keys
            int hist[256];
            int wsum[4];
            unsigned long long blist[512];     // boundary-bucket members
        } k;
        struct {
            float xs_t[MM][36];
            float u[MM][20];
            float nfs[CC + 1][MM];             // row 35 zeroed (pad for packed w1)
            float h1s[64][36];
            float h2s[64][36];
            float pmax[128][2];
        } a;
    };
    __shared__ Smem S;
    __shared__ int idxs[MM];
    __shared__ int scal[4];                    // [0]=B [1]=cntBelow [2]=nB [3]=outcnt

    // ================= kNN phase (exact: contract off) =================
    {
#pragma clang fp contract(off)
        const float* xb = xyz + b * NN * 3;
        const float qx = newxyz[bp * 3 + 0];
        const float qy = newxyz[bp * 3 + 1];
        const float qz = newxyz[bp * 3 + 2];
        const float qn = (qx * qx + qy * qy) + qz * qz;

        S.k.hist[t] = 0;
        if (t < 4) scal[t] = 0;
        __syncthreads();

#pragma unroll
        for (int k = 0; k < 16; ++k) {
            int n = t + 256 * k;
            float x = xb[n * 3 + 0], y = xb[n * 3 + 1], z = xb[n * 3 + 2];
            float xn = (x * x + y * y) + z * z;
            float dt = (qx * x + qy * y) + qz * z;
            float d = (qn + xn) - 2.0f * dt;
            unsigned bits = __float_as_uint(d);
            unsigned kx = bits ^ ((unsigned)((int)bits >> 31) | 0x80000000u);
            S.k.kxs[n] = kx;
            atomicAdd(&S.k.hist[kx >> 24], 1);
        }
        __syncthreads();

        {   // prefix over 256 buckets; locate boundary bucket
            int c = S.k.hist[t];
            int incl = c;
            const int lane = t & 63, w = t >> 6;
#pragma unroll
            for (int off = 1; off < 64; off <<= 1) {
                int o = __shfl_up(incl, off);
                if (lane >= off) incl += o;
            }
            if (lane == 63) S.k.wsum[w] = incl;
            __syncthreads();
            int base = 0;
            for (int ww = 0; ww < 4; ++ww) if (ww < w) base += S.k.wsum[ww];
            int excl = base + incl - c;
            if (excl < MM && MM <= excl + c) { scal[0] = t; scal[1] = excl; }
        }
        __syncthreads();

        const int B = scal[0];
        const int cntBelow = scal[1];
        const unsigned bstart = (unsigned)B << 24;

#pragma unroll
        for (int k = 0; k < 16; ++k) {
            int n = t + 256 * k;
            unsigned kx = S.k.kxs[n];
            if (kx < bstart) {
                int pos = atomicAdd(&scal[3], 1);
                idxs[pos] = n;
            } else if ((kx >> 24) == (unsigned)B) {
                int pos = atomicAdd(&scal[2], 1);
                if (pos < 512) S.k.blist[pos] = ((unsigned long long)kx << 32) | (unsigned)n;
            }
        }
        __syncthreads();

        const int nB = scal[2];
        const int k2 = MM - cntBelow;

        if (nB <= 512) {
            for (int m = t; m < nB; m += 256) {
                unsigned long long my = S.k.blist[m];
                int rank = 0;
                for (int q = 0; q < nB; ++q) rank += (S.k.blist[q] < my) ? 1 : 0;
                if (rank < k2)
                    idxs[cntBelow + rank] = (int)(my & 0xFFFFFFFFu);
            }
        } else {
            // fallback (pathological duplicates): serial exact selection
            for (int r = 0; r < MM; ++r) {
                unsigned bvk = 0xFFFFFFFFu; int bi = NN;
#pragma unroll
                for (int k = 0; k < 16; ++k) {
                    int n = t + 256 * k;
                    unsigned v = S.k.kxs[n];
                    if (v < bvk) { bvk = v; bi = n; }
                }
#pragma unroll
                for (int off = 1; off < 64; off <<= 1) {
                    unsigned ov = __shfl_xor(bvk, off);
                    int   oi = __shfl_xor(bi, off);
                    if (ov < bvk || (ov == bvk && oi < bi)) { bvk = ov; bi = oi; }
                }
                if ((t & 63) == 0) { S.k.hist[t >> 6] = (int)bvk; S.k.wsum[t >> 6] = bi; }
                __syncthreads();
                unsigned fv = (unsigned)S.k.hist[0]; int fi = S.k.wsum[0];
#pragma unroll
                for (int w = 1; w < 4; ++w) {
                    unsigned ov = (unsigned)S.k.hist[w]; int oi = S.k.wsum[w];
                    if (ov < fv || (ov == fv && oi < fi)) { fv = ov; fi = oi; }
                }
                if (t == 0) { idxs[r] = fi; S.k.kxs[fi] = 0xFFFFFFFFu; }
                __syncthreads();
            }
        }
    }
    __syncthreads();   // knn buffers dead; afa buffers live from here

    // ================= gather x = concat(gxyz, gfeat) as [m][c] =================
    {
        const int m = t & 31, c0 = t >> 5;
        const int id = idxs[m] & (NN - 1);
        for (int c = c0; c < CC; c += 8) {
            float v;
            if (c < 3) v = xyz[(b * NN + id) * 3 + c] - newxyz[bp * 3 + c];
            else       v = feat[(b * CIN + (c - 3)) * NN + id];
            S.a.xs_t[m][c] = v;
        }
        if (c0 == 0) S.a.xs_t[m][35] = 0.0f;
    }
    __syncthreads();

    const int i = t >> 3, jg = t & 7;

    float xi[36];
    {
        const float4* xp = (const float4*)&S.a.xs_t[i][0];
#pragma unroll
        for (int q = 0; q < 9; ++q) {
            float4 v = xp[q];
            xi[4 * q] = v.x; xi[4 * q + 1] = v.y; xi[4 * q + 2] = v.z; xi[4 * q + 3] = v.w;
        }
    }

    // ---- phase A (u-split): thread (i,jg) computes o = 2jg, 2jg+1 only
#pragma unroll
    for (int oo = 0; oo < 2; ++oo) {
        const int o = 2 * jg + oo;
        float acc = 0.0f;
#pragma unroll
        for (int c = 0; c < CC; ++c) acc += aw1[o * CC + c] * xi[c];
        S.a.u[i][o] = acc;
    }
    __syncthreads();

    float ui[16];
    {
        const float4* up = (const float4*)&S.a.u[i][0];
#pragma unroll
        for (int q = 0; q < 4; ++q) {
            float4 v = up[q];
            ui[4 * q] = v.x; ui[4 * q + 1] = v.y; ui[4 * q + 2] = v.z; ui[4 * q + 3] = v.w;
        }
    }

    // ---- phase B: per pair (i, j = jg+8*jk)
    float afa[CC];
#pragma unroll
    for (int c = 0; c < CC; ++c) afa[c] = 0.0f;

#pragma unroll
    for (int jk = 0; jk < 4; ++jk) {
        const int j = jg + 8 * jk;
        const bool diag = (i == j);

        float uj[16];
        {
            const float4* up = (const float4*)&S.a.u[j][0];
#pragma unroll
            for (int q = 0; q < 4; ++q) {
                float4 v = up[q];
                uj[4 * q] = v.x; uj[4 * q + 1] = v.y; uj[4 * q + 2] = v.z; uj[4 * q + 3] = v.w;
            }
        }

        float h1[16];
#pragma unroll
        for (int o = 0; o < 16; ++o) {
            float sv = ui[o] - uj[o];
            if (diag) sv += ui[o];
            h1[o] = fmaxf(sv + ab1[o], 0.0f);
        }

        float xj[36];
        {
            const float4* xp = (const float4*)&S.a.xs_t[j][0];
#pragma unroll
            for (int q = 0; q < 9; ++q) {
                float4 v = xp[q];
                xj[4 * q] = v.x; xj[4 * q + 1] = v.y; xj[4 * q + 2] = v.z; xj[4 * q + 3] = v.w;
            }
        }

        float h2[16];
#pragma unroll
        for (int o = 0; o < 16; ++o) {
            float acc = ab2[o];
#pragma unroll
            for (int c = 0; c < 16; ++c) acc += aw2[o * 16 + c] * h1[c];
            h2[o] = fmaxf(acc, 0.0f);
        }

#pragma unroll
        for (int c = 0; c < CC; ++c) {
            float acc = abw[c];
#pragma unroll
            for (int k = 0; k < 16; ++k) acc += aww[c * 16 + k] * h2[k];
            float pc_ = xi[c] - xj[c];
            if (diag) pc_ += xi[c];
            afa[c] += pc_ * acc;
        }
    }

    // reduce afa across 8 lanes sharing i; nf = x + afa as [c][m]; zero pad row
#pragma unroll
    for (int c = 0; c < CC; ++c) {
        float v = afa[c];
        v += __shfl_xor(v, 1);
        v += __shfl_xor(v, 2);
        v += __shfl_xor(v, 4);
        if (jg == 0) S.a.nfs[c][i] = xi[c] + v;
    }
    if (jg == 0) S.a.nfs[35][i] = 0.0f;
    __syncthreads();

    // ---- MLP layer 1: 35 -> 64 (packed w1p [9][64][4]; c=35 pad term is exactly 0)
    {
        const int o = t & 63, ib = (t >> 6) << 3;
        float acc[8];
        float bb = b1[o];
#pragma unroll
        for (int k = 0; k < 8; ++k) acc[k] = bb;
        const float4* wp = (const float4*)w1p;
#pragma unroll
        for (int c4 = 0; c4 < 9; ++c4) {
            float4 w = wp[c4 * 64 + o];
#pragma unroll
            for (int cl = 0; cl < 4; ++cl) {
                const int c = 4 * c4 + cl;
                float wc = ((const float*)&w)[cl];
                const float4* np4 = (const float4*)&S.a.nfs[c][ib];
                float4 n0 = np4[0], n1 = np4[1];
                acc[0] += wc * n0.x; acc[1] += wc * n0.y; acc[2] += wc * n0.z; acc[3] += wc * n0.w;
                acc[4] += wc * n1.x; acc[5] += wc * n1.y; acc[6] += wc * n1.z; acc[7] += wc * n1.w;
            }
        }
        float4 r0 = { fmaxf(acc[0], 0.0f), fmaxf(acc[1], 0.0f), fmaxf(acc[2], 0.0f), fmaxf(acc[3], 0.0f) };
        float4 r1 = { fmaxf(acc[4], 0.0f), fmaxf(acc[5], 0.0f), fmaxf(acc[6], 0.0f), fmaxf(acc[7], 0.0f) };
        *(float4*)&S.a.h1s[o][ib]     = r0;
        *(float4*)&S.a.h1s[o][ib + 4] = r1;
    }
    __syncthreads();

    // ---- MLP layer 2: 64 -> 64 (packed w2p [16][64][4])
    {
        const int o = t & 63, ib = (t >> 6) << 3;
        float acc[8];
        float bb = b2[o];
#pragma unroll
        for (int k = 0; k < 8; ++k) acc[k] = bb;
        const float4* wp = (const float4*)w2p;
#pragma unroll
        for (int c4 = 0; c4 < 16; ++c4) {
            float4 w = wp[c4 * 64 + o];
#pragma unroll
            for (int cl = 0; cl < 4; ++cl) {
                const int c = 4 * c4 + cl;
                float wc = ((const float*)&w)[cl];
                const float4* hp4 = (const float4*)&S.a.h1s[c][ib];
                float4 h0 = hp4[0], h1v = hp4[1];
                acc[0] += wc * h0.x; acc[1] += wc * h0.y; acc[2] += wc * h0.z; acc[3] += wc * h0.w;
                acc[4] += wc * h1v.x; acc[5] += wc * h1v.y; acc[6] += wc * h1v.z; acc[7] += wc * h1v.w;
            }
        }
        float4 r0 = { fmaxf(acc[0], 0.0f), fmaxf(acc[1], 0.0f), fmaxf(acc[2], 0.0f), fmaxf(acc[3], 0.0f) };
        float4 r1 = { fmaxf(acc[4], 0.0f), fmaxf(acc[5], 0.0f), fmaxf(acc[6], 0.0f), fmaxf(acc[7], 0.0f) };
        *(float4*)&S.a.h2s[o][ib]     = r0;
        *(float4*)&S.a.h2s[o][ib + 4] = r1;
    }
    __syncthreads();

    // ---- MLP layer 3: 64 -> 128 (packed w3p [16][128][4]), relu, maxpool over M
    {
        const int o = t & 127, ib = (t >> 7) << 4;
        float acc[16];
        float bb = b3[o];
#pragma unroll
        for (int k = 0; k < 16; ++k) acc[k] = bb;
        const float4* wp = (const float4*)w3p;
#pragma unroll
        for (int c4 = 0; c4 < 16; ++c4) {
            float4 w = wp[c4 * 128 + o];
#pragma unroll
            for (int cl = 0; cl < 4; ++cl) {
                const int c = 4 * c4 + cl;
                float wc = ((const float*)&w)[cl];
                const float4* hp4 = (const float4*)&S.a.h2s[c][ib];
                float4 h0 = hp4[0], h1v = hp4[1], h2v = hp4[2], h3v = hp4[3];
                acc[0]  += wc * h0.x;  acc[1]  += wc * h0.y;  acc[2]  += wc * h0.z;  acc[3]  += wc * h0.w;
                acc[4]  += wc * h1v.x; acc[5]  += wc * h1v.y; acc[6]  += wc * h1v.z; acc[7]  += wc * h1v.w;
                acc[8]  += wc * h2v.x; acc[9]  += wc * h2v.y; acc[10] += wc * h2v.z; acc[11] += wc * h2v.w;
                acc[12] += wc * h3v.x; acc[13] += wc * h3v.y; acc[14] += wc * h3v.z; acc[15] += wc * h3v.w;
            }
        }
        float mx = -1e30f;
#pragma unroll
        for (int k = 0; k < 16; ++k) mx = fmaxf(mx, fmaxf(acc[k], 0.0f));
        S.a.pmax[o][t >> 7] = mx;
    }
    __syncthreads();

    if (t < 128) {
        float v = fmaxf(S.a.pmax[t][0], S.a.pmax[t][1]);
        out[(b * 128 + t) * NP + p] = v;
    }
}

extern "C" void kernel_launch(void* const* d_in, const int* in_sizes, int n_in,
                              void* d_out, int out_size, void* d_ws, size_t ws_size,
                              hipStream_t stream)
{
    const float* xyz  = (const float*)d_in[0];
    const float* feat = (const float*)d_in[1];
    const float* aw1  = (const float*)d_in[2];
    const float* ab1  = (const float*)d_in[3];
    const float* aw2  = (const float*)d_in[4];
    const float* ab2  = (const float*)d_in[5];
    const float* aww  = (const float*)d_in[6];
    const float* abw  = (const float*)d_in[7];
    const float* mw1  = (const float*)d_in[8];
    const float* mb1  = (const float*)d_in[9];
    const float* mw2  = (const float*)d_in[10];
    const float* mb2  = (const float*)d_in[11];
    const float* mw3  = (const float*)d_in[12];
    const float* mb3  = (const float*)d_in[13];

    float* out    = (float*)d_out;
    float* newxyz = out;                  // (B, NP, 3) = 6144 floats
    float* out2   = out + BB * NP * 3;    // (B, 128, NP)

    float* w1p = (float*)d_ws;            // [9][64][4]   = 2304 floats
    float* w2p = w1p + 9 * 64 * 4;        // [16][64][4]  = 4096 floats
    float* w3p = w2p + 16 * 64 * 4;       // [16][128][4] = 8192 floats

    fps_prep_kernel<<<dim3(BB + 8), dim3(256), 0, stream>>>(xyz, newxyz,
                                                            mw1, mw2, mw3, w1p, w2p, w3p);
    knnafa_kernel<<<dim3(BB * NP), dim3(256), 0, stream>>>(
        xyz, feat, newxyz,
        aw1, ab1, aw2, ab2, aww, abw,
        w1p, mb1, w2p, mb2, w3p, mb3, out2);
}